// Round 5
// baseline (730.769 us; speedup 1.0000x reference)
//
#include <hip/hip_runtime.h>

#define Bb 32
#define Tt 64
#define Nn 300
#define Dd 128
#define NC (Nn * Dd)              // 38400 columns per (b,t) row
#define BTND ((size_t)Tt * NC)    // 2457600 elems per batch

// Kernel 1: fused Q[b,t,n] = sum_d src*wt1  and  K[b,t,d] = sum_n wt3*src.
// One block per (b,t); 8 half-wave groups; group g covers row n0+g, lane
// covers 4 consecutive d (float4). Round-5 change: the Q row-reduce is
// 1 shfl + LDS-partial (qpart[n][17-pad], stage-B sum of 16) instead of
// 5 shfl/row: DS-pipe ops/wave drop ~375 -> ~110, LDS 25.7 KB -> 6
// blocks/CU (75% occ) so the kernel runs at its ~50 us HBM floor.
__global__ __launch_bounds__(256) void qk_kernel(
        const float* __restrict__ src, const float* __restrict__ wt1,
        const float* __restrict__ wt3, float* __restrict__ Q,
        float* __restrict__ K) {
    __shared__ float wt3_s[Nn];
    __shared__ float qpart[Nn * 17];  // [n][16 partials + 1 pad] = 20.4 KB
    __shared__ float kred[8 * Dd];    // 8 groups x 128 d = 4 KB
    const int tid = threadIdx.x;
    const int grp = tid >> 5;       // 0..7
    const int gl = tid & 31;        // lane within group
    for (int i = tid; i < Nn; i += 256) wt3_s[i] = wt3[i];
    __syncthreads();
    const int d0 = gl * 4;
    const float4 w1 = *(const float4*)(wt1 + d0);
    const float* sbt = src + (size_t)blockIdx.x * NC;
    float* Qrow = Q + (size_t)blockIdx.x * Nn;
    float4 k = {0.f, 0.f, 0.f, 0.f};
    // 300 = 37*8 + 4: main loop guard-free over rows 0..295, tail 296..299.
    #pragma unroll 2
    for (int n0 = 0; n0 < 296; n0 += 8) {
        const int n = n0 + grp;
        float4 v = *(const float4*)(sbt + n * Dd + d0);
        float p = v.x * w1.x + v.y * w1.y + v.z * w1.z + v.w * w1.w;
        p += __shfl_down(p, 16, 32);
        if (gl < 16) qpart[n * 17 + gl] = p;
        const float w3 = wt3_s[n];
        k.x = fmaf(w3, v.x, k.x);
        k.y = fmaf(w3, v.y, k.y);
        k.z = fmaf(w3, v.z, k.z);
        k.w = fmaf(w3, v.w, k.w);
    }
    if (grp < 4) {
        const int n = 296 + grp;
        float4 v = *(const float4*)(sbt + n * Dd + d0);
        float p = v.x * w1.x + v.y * w1.y + v.z * w1.z + v.w * w1.w;
        p += __shfl_down(p, 16, 32);
        if (gl < 16) qpart[n * 17 + gl] = p;
        const float w3 = wt3_s[n];
        k.x = fmaf(w3, v.x, k.x);
        k.y = fmaf(w3, v.y, k.y);
        k.z = fmaf(w3, v.z, k.z);
        k.w = fmaf(w3, v.w, k.w);
    }
    *(float4*)(kred + grp * Dd + d0) = k;
    __syncthreads();
    // K final reduce (4 waves worth of threads idle-cheap)
    if (tid < Dd) {
        float s = 0.f;
        #pragma unroll
        for (int g = 0; g < 8; ++g) s += kred[g * Dd + tid];
        K[(size_t)blockIdx.x * Dd + tid] = s;
    }
    // Q final reduce: thread r sums 16 partials of row r. Bank-free: addr
    // = 17*r + i, 17 odd -> 64 lanes spread 2-per-bank (free).
    for (int r = tid; r < Nn; r += 256) {
        float s = 0.f;
        #pragma unroll
        for (int i = 0; i < 16; ++i) s += qpart[r * 17 + i];
        Qrow[r] = s;
    }
}

// Kernel 2: scores[b,q,k] = sum_d (sum_n Q[b,q,n]*wt2[n,d]) * K[b,k,d].
// One block per (b,q); 128 threads. Round-5 change: both phases use 4
// independent accumulators so loads pipeline instead of serializing on a
// single fmaf chain (QW was 300 dependent load+fma iterations).
__global__ __launch_bounds__(128) void score_kernel(
        const float* __restrict__ Q, const float* __restrict__ K,
        const float* __restrict__ wt2, float* __restrict__ scores) {
    __shared__ float qs[Nn];
    __shared__ float qws[Dd];
    const int tid = threadIdx.x;
    const int bq = blockIdx.x;  // b*T + q
    const float* Qrow = Q + (size_t)bq * Nn;
    for (int i = tid; i < Nn; i += 128) qs[i] = Qrow[i];
    __syncthreads();
    float qw0 = 0.f, qw1 = 0.f, qw2 = 0.f, qw3 = 0.f;
    for (int n = 0; n < Nn; n += 4) {  // 300 = 4*75 exact
        qw0 = fmaf(qs[n + 0], wt2[(n + 0) * Dd + tid], qw0);
        qw1 = fmaf(qs[n + 1], wt2[(n + 1) * Dd + tid], qw1);
        qw2 = fmaf(qs[n + 2], wt2[(n + 2) * Dd + tid], qw2);
        qw3 = fmaf(qs[n + 3], wt2[(n + 3) * Dd + tid], qw3);
    }
    qws[tid] = (qw0 + qw1) + (qw2 + qw3);
    __syncthreads();
    if (tid < Tt) {
        const int b = bq >> 6;  // T = 64
        const float* Krow = K + (size_t)(b * Tt + tid) * Dd;
        float s0 = 0.f, s1 = 0.f, s2 = 0.f, s3 = 0.f;
        for (int d = 0; d < Dd; d += 4) {  // 128 = 4*32 exact
            s0 = fmaf(qws[d + 0], Krow[d + 0], s0);
            s1 = fmaf(qws[d + 1], Krow[d + 1], s1);
            s2 = fmaf(qws[d + 2], Krow[d + 2], s2);
            s3 = fmaf(qws[d + 3], Krow[d + 3], s3);
        }
        scores[(size_t)bq * Tt + tid] = (s0 + s1) + (s2 + s3);
    }
}

// Kernel 3: softmax over the BATCH axis (axis 0), per (q,k) pair.
// Writes att + I (identity folded: idx = q*64+k, q==k <=> idx%65==0).
__global__ __launch_bounds__(64) void softmax_b_kernel(
        const float* __restrict__ scores, float* __restrict__ att) {
    const int idx = blockIdx.x * 64 + threadIdx.x;  // qk index in [0, T*T)
    float v[Bb];
    float m = -1e30f;
    #pragma unroll
    for (int b = 0; b < Bb; ++b) {
        v[b] = scores[b * (Tt * Tt) + idx];
        m = fmaxf(m, v[b]);
    }
    float sum = 0.f;
    #pragma unroll
    for (int b = 0; b < Bb; ++b) {
        float e = __expf(v[b] - m);
        v[b] = e;
        sum += e;
    }
    const float inv = 1.0f / sum;
    const float diag = (idx % 65 == 0) ? 1.0f : 0.0f;
    #pragma unroll
    for (int b = 0; b < Bb; ++b) att[b * (Tt * Tt) + idx] = v[b] * inv + diag;
}

// Kernel 4: out[b,a,j] = sum_t attI[b,t,a] * src[b,t,j]  (attI = att + I).
// 512 thr = 8 waves; wave w owns a in [8w,8w+8); lane owns 8 consecutive j.
// acc[8][8]=64 regs (AGPR-split: VGPR 60 + ~64 AGPR = just under the
// (512,4) cap of 128). Proven 220 us @ 37% VALUBusy — unchanged this round.
//   round-1: (512,2) -> 1 block/CU -> latency-bound, 271 us.
//   round-2: (512,6) -> cap 85 -> acc spilled, 1613 us.
//   round-3: per-iter uniform s_load att reads serialize, 340 us.
#define MIX_JT 512  // j floats per block: 64 lanes * 8
__global__ __launch_bounds__(512, 4) void mix_kernel(
        const float* __restrict__ src, const float* __restrict__ attI,
        float* __restrict__ out) {
    __shared__ float att_s[Tt * Tt];  // [t][a], 16 KB
    const int tid = threadIdx.x;
    const int b = blockIdx.y;
    for (int i = tid; i < Tt * Tt; i += 512)
        att_s[i] = attI[(size_t)b * Tt * Tt + i];
    __syncthreads();
    const int wave = tid >> 6, lane = tid & 63;
    const int a0 = wave * 8;
    const int j = blockIdx.x * MIX_JT + lane * 8;
    const float* sb = src + (size_t)b * BTND + j;
    float* ob = out + (size_t)b * BTND + j;
    float acc[8][8];
    #pragma unroll
    for (int ai = 0; ai < 8; ++ai)
        #pragma unroll
        for (int jj = 0; jj < 8; ++jj) acc[ai][jj] = 0.f;
    float4 x0 = *(const float4*)(sb);
    float4 x1 = *(const float4*)(sb + 4);
    for (int t = 0; t < Tt; ++t) {
        const int tn = (t < Tt - 1) ? t + 1 : t;
        const float4 n0 = *(const float4*)(sb + (size_t)tn * NC);
        const float4 n1 = *(const float4*)(sb + (size_t)tn * NC + 4);
        const float4 av0 = *(const float4*)(att_s + t * Tt + a0);
        const float4 av1 = *(const float4*)(att_s + t * Tt + a0 + 4);
        const float av[8] = {av0.x, av0.y, av0.z, av0.w,
                             av1.x, av1.y, av1.z, av1.w};
        const float xv[8] = {x0.x, x0.y, x0.z, x0.w,
                             x1.x, x1.y, x1.z, x1.w};
        #pragma unroll
        for (int ai = 0; ai < 8; ++ai)
            #pragma unroll
            for (int jj = 0; jj < 8; ++jj)
                acc[ai][jj] = fmaf(av[ai], xv[jj], acc[ai][jj]);
        x0 = n0;
        x1 = n1;
    }
    #pragma unroll
    for (int ai = 0; ai < 8; ++ai) {
        float* orow = ob + (size_t)(a0 + ai) * NC;
        float4 s0 = {acc[ai][0], acc[ai][1], acc[ai][2], acc[ai][3]};
        float4 s1 = {acc[ai][4], acc[ai][5], acc[ai][6], acc[ai][7]};
        *(float4*)(orow) = s0;
        *(float4*)(orow + 4) = s1;
    }
}

extern "C" void kernel_launch(void* const* d_in, const int* in_sizes, int n_in,
                              void* d_out, int out_size, void* d_ws, size_t ws_size,
                              hipStream_t stream) {
    const float* src = (const float*)d_in[0];
    const float* wt1 = (const float*)d_in[1];
    const float* wt2 = (const float*)d_in[2];
    const float* wt3 = (const float*)d_in[3];
    float* out = (float*)d_out;

    float* ws = (float*)d_ws;
    float* Q      = ws;                               // B*T*N  = 614400 floats
    float* K      = Q + (size_t)Bb * Tt * Nn;         // B*T*D  = 262144 floats
    float* scores = K + (size_t)Bb * Tt * Dd;         // B*T*T  = 131072 floats
    float* att    = scores + (size_t)Bb * Tt * Tt;    // B*T*T  = 131072 floats
    // total ws use: ~4.6 MB

    qk_kernel<<<Bb * Tt, 256, 0, stream>>>(src, wt1, wt3, Q, K);
    score_kernel<<<Bb * Tt, 128, 0, stream>>>(Q, K, wt2, scores);
    softmax_b_kernel<<<(Tt * Tt) / 64, 64, 0, stream>>>(scores, att);
    dim3 g4(NC / MIX_JT, Bb);
    mix_kernel<<<g4, 512, 0, stream>>>(src, att, out);
}

// Round 6
// 657.149 us; speedup vs baseline: 1.1120x; 1.1120x over previous
//
#include <hip/hip_runtime.h>

#define Bb 32
#define Tt 64
#define Nn 300
#define Dd 128
#define NC (Nn * Dd)              // 38400 columns per (b,t) row
#define BTND ((size_t)Tt * NC)    // 2457600 elems per batch

// Kernel 1: fused  Q[bt,n] = sum_d src*wt1   (kept in LDS only)
//                  K[bt,d] = sum_n wt3*src
//                  QW[bt,d] = sum_n Q[bt,n]*wt2[n,d]   (score's 1st phase,
//                  fused here because the Q row is block-local and wt2
//                  reads coalesce across threads; kills the Q workspace).
// One block per bt; 8 half-wave groups; group g does row n0+g, lane covers
// 4 consecutive d (float4, coalesced 512 B per group-load).
__global__ __launch_bounds__(256) void qkw_kernel(
        const float* __restrict__ src, const float* __restrict__ wt1,
        const float* __restrict__ wt2, const float* __restrict__ wt3,
        float* __restrict__ QW, float* __restrict__ K) {
    __shared__ float wt3_s[Nn];
    __shared__ float qs[Nn];        // Q row, consumed in-block by QW phase
    __shared__ float kred[8 * Dd];  // 8 groups x 128 d = 4 KB
    const int tid = threadIdx.x;
    const int grp = tid >> 5;       // 0..7
    const int gl = tid & 31;        // lane within group
    for (int i = tid; i < Nn; i += 256) wt3_s[i] = wt3[i];
    __syncthreads();
    const int d0 = gl * 4;
    const float4 w1 = *(const float4*)(wt1 + d0);
    const float* sbt = src + (size_t)blockIdx.x * NC;
    float4 k = {0.f, 0.f, 0.f, 0.f};
    for (int n0 = 0; n0 < Nn; n0 += 8) {
        const int n = n0 + grp;
        if (n < Nn) {  // 300 = 8*37+4: groups 4..7 idle on the last iter
            float4 v = *(const float4*)(sbt + n * Dd + d0);
            float q = v.x * w1.x + v.y * w1.y + v.z * w1.z + v.w * w1.w;
            #pragma unroll
            for (int off = 16; off > 0; off >>= 1) q += __shfl_down(q, off, 32);
            if (gl == 0) qs[n] = q;
            const float w3 = wt3_s[n];
            k.x = fmaf(w3, v.x, k.x);
            k.y = fmaf(w3, v.y, k.y);
            k.z = fmaf(w3, v.z, k.z);
            k.w = fmaf(w3, v.w, k.w);
        }
    }
    *(float4*)(kred + grp * Dd + d0) = k;
    __syncthreads();
    if (tid < Dd) {
        float s = 0.f;
        #pragma unroll
        for (int g = 0; g < 8; ++g) s += kred[g * Dd + tid];
        K[(size_t)blockIdx.x * Dd + tid] = s;
        // QW phase: thread = d. qs[n] is a free LDS broadcast; wt2 reads
        // coalesce (128 consecutive floats per wave-load). 4 indep chains.
        const float* w2c = wt2 + tid;
        float qw0 = 0.f, qw1 = 0.f, qw2 = 0.f, qw3 = 0.f;
        for (int n = 0; n < Nn; n += 4) {  // 300 = 4*75 exact
            qw0 = fmaf(qs[n + 0], w2c[(n + 0) * Dd], qw0);
            qw1 = fmaf(qs[n + 1], w2c[(n + 1) * Dd], qw1);
            qw2 = fmaf(qs[n + 2], w2c[(n + 2) * Dd], qw2);
            qw3 = fmaf(qs[n + 3], w2c[(n + 3) * Dd], qw3);
        }
        QW[(size_t)blockIdx.x * Dd + tid] = (qw0 + qw1) + (qw2 + qw3);
    }
}

// Kernel 2: fused scores + batch-softmax, replacing the old score kernel
// whose 2nd phase was fully UNCOALESCED (thread=k read K rows 512 B apart:
// 64 cache lines per wave-load, ~16.8M serialized line-requests — the
// prime suspect for the 470 us residual that never responded to tuning).
// Block = (k, q) via dim3(64,64); 128 thr = 4 groups x 32 lanes; group bg
// handles b = 8*bg..8*bg+7 serially. All QW/K loads are coalesced float4.
// Softmax over b runs in-block on the 32 LDS scores; writes att + I.
__global__ __launch_bounds__(128) void score_softmax_kernel(
        const float* __restrict__ QW, const float* __restrict__ K,
        float* __restrict__ att) {
    __shared__ float sc[Bb];
    const int kk = blockIdx.x, q = blockIdx.y;
    const int tid = threadIdx.x;
    const int bg = tid >> 5, gl = tid & 31;
    const int d0 = gl * 4;
    #pragma unroll
    for (int i = 0; i < 8; ++i) {
        const int b = bg * 8 + i;
        const float4 qw = *(const float4*)(QW + ((size_t)b * Tt + q) * Dd + d0);
        const float4 kv = *(const float4*)(K + ((size_t)b * Tt + kk) * Dd + d0);
        float p = qw.x * kv.x + qw.y * kv.y + qw.z * kv.z + qw.w * kv.w;
        #pragma unroll
        for (int off = 16; off > 0; off >>= 1) p += __shfl_down(p, off, 32);
        if (gl == 0) sc[b] = p;
    }
    __syncthreads();
    float m = -1e30f;
    #pragma unroll
    for (int b = 0; b < Bb; ++b) m = fmaxf(m, sc[b]);  // LDS broadcast, uniform
    float sum = 0.f;
    #pragma unroll
    for (int b = 0; b < Bb; ++b) sum += __expf(sc[b] - m);
    if (tid < Bb) {
        const float diag = (q == kk) ? 1.0f : 0.0f;
        att[(size_t)tid * (Tt * Tt) + q * Tt + kk] =
            __expf(sc[tid] - m) / sum + diag;
    }
}

// Kernel 3: out[b,a,j] = sum_t attI[b,t,a] * src[b,t,j]  (attI = att + I).
// Round-6 change: acc[8][4] (32 regs) instead of acc[8][8] so that
// __launch_bounds__(512, 6) -> 3 blocks/CU (24 waves, 75% occ) fits under
// the ~85-reg cap (est. ~60 used). Round-4 version was latency-limited at
// 36% occ / 37% VALUBusy / 220 us; VALU floor 64 us, HBM floor ~95 us.
//   round-1: (512,2) -> 1 block/CU -> latency-bound, 271 us.
//   round-2: (512,6) + 64 acc -> spill, 1613 us (32 acc has 2x margin).
//   round-3: per-iter uniform s_load att reads serialize, 340 us.
#define MIX_JT 256  // j floats per block: 64 lanes * 4
__global__ __launch_bounds__(512, 6) void mix_kernel(
        const float* __restrict__ src, const float* __restrict__ attI,
        float* __restrict__ out) {
    __shared__ float att_s[Tt * Tt];  // [t][a], 16 KB
    const int tid = threadIdx.x;
    const int b = blockIdx.y;
    for (int i = tid; i < Tt * Tt; i += 512)
        att_s[i] = attI[(size_t)b * Tt * Tt + i];
    __syncthreads();
    const int wave = tid >> 6, lane = tid & 63;
    const int a0 = wave * 8;
    const int j = blockIdx.x * MIX_JT + lane * 4;
    const float* sb = src + (size_t)b * BTND + j;
    float* ob = out + (size_t)b * BTND + j;
    float acc[8][4];
    #pragma unroll
    for (int ai = 0; ai < 8; ++ai)
        #pragma unroll
        for (int jj = 0; jj < 4; ++jj) acc[ai][jj] = 0.f;
    float4 x = *(const float4*)sb;
    for (int t = 0; t < Tt; ++t) {
        const int tn = (t < Tt - 1) ? t + 1 : t;
        const float4 xn = *(const float4*)(sb + (size_t)tn * NC);
        const float4 av0 = *(const float4*)(att_s + t * Tt + a0);
        const float4 av1 = *(const float4*)(att_s + t * Tt + a0 + 4);
        const float av[8] = {av0.x, av0.y, av0.z, av0.w,
                             av1.x, av1.y, av1.z, av1.w};
        #pragma unroll
        for (int ai = 0; ai < 8; ++ai) {
            acc[ai][0] = fmaf(av[ai], x.x, acc[ai][0]);
            acc[ai][1] = fmaf(av[ai], x.y, acc[ai][1]);
            acc[ai][2] = fmaf(av[ai], x.z, acc[ai][2]);
            acc[ai][3] = fmaf(av[ai], x.w, acc[ai][3]);
        }
        x = xn;
    }
    #pragma unroll
    for (int ai = 0; ai < 8; ++ai) {
        float4 s = {acc[ai][0], acc[ai][1], acc[ai][2], acc[ai][3]};
        *(float4*)(ob + (size_t)(a0 + ai) * NC) = s;
    }
}

extern "C" void kernel_launch(void* const* d_in, const int* in_sizes, int n_in,
                              void* d_out, int out_size, void* d_ws, size_t ws_size,
                              hipStream_t stream) {
    const float* src = (const float*)d_in[0];
    const float* wt1 = (const float*)d_in[1];
    const float* wt2 = (const float*)d_in[2];
    const float* wt3 = (const float*)d_in[3];
    float* out = (float*)d_out;

    float* ws = (float*)d_ws;
    float* QW  = ws;                               // B*T*D = 262144 floats
    float* K   = QW + (size_t)Bb * Tt * Dd;        // B*T*D = 262144 floats
    float* att = K + (size_t)Bb * Tt * Dd;         // B*T*T = 131072 floats
    // total ws use: ~2.6 MB

    qkw_kernel<<<Bb * Tt, 256, 0, stream>>>(src, wt1, wt2, wt3, QW, K);
    dim3 g2(Tt, Tt);
    score_softmax_kernel<<<g2, 128, 0, stream>>>(QW, K, att);
    dim3 g3(NC / MIX_JT, Bb);
    mix_kernel<<<g3, 512, 0, stream>>>(src, att, out);
}